// Round 9
// baseline (4282.547 us; speedup 1.0000x reference)
//
#include <hip/hip_runtime.h>
#include <hip/hip_bf16.h>
#include <math.h>

#define BB 64
#define IMG 224
#define PP 16
#define CIN 3
#define DM 192
#define DEPTH 24
#define DSTATE 16
#define DINNER 384
#define DTR 12
#define DCONV 4
#define NP 196              // (224/16)^2
#define RTOT (BB * NP)      // 12544 rows
#define CHUNKS 14
#define LC 14               // NP / CHUNKS

typedef short bf16x8 __attribute__((ext_vector_type(8)));
typedef float f32x4 __attribute__((ext_vector_type(4)));

__device__ inline unsigned short f2bf_rne(float f) {
    unsigned u = __float_as_uint(f);
    unsigned r = u + 0x7fffu + ((u >> 16) & 1u);
    return (unsigned short)(r >> 16);
}
__device__ inline float bf2f(unsigned short s) {
    return __uint_as_float(((unsigned)s) << 16);
}

// ---------------- im2col for patch embed, emitting packed hi/lo bf16 planes ----------------
__global__ __launch_bounds__(256) void im2col_pack_kernel(const float* __restrict__ img,
                                                          short* __restrict__ colH,
                                                          short* __restrict__ colL) {
    size_t idx = (size_t)blockIdx.x * 256 + threadIdx.x;
    if (idx >= (size_t)RTOT * 768) return;
    int t = (int)(idx % 768);
    size_t r = idx / 768;
    int l = (int)(r % NP);
    int b = (int)(r / NP);
    int ph = l / 14, pw = l % 14;
    int ci = t / 256, rem = t % 256;
    int i = rem / 16, j = rem % 16;
    float v = img[(((size_t)b * CIN + ci) * IMG + ph * 16 + i) * IMG + pw * 16 + j];
    unsigned short hs = f2bf_rne(v);
    colH[idx] = (short)hs;
    colL[idx] = (short)f2bf_rne(v - bf2f(hs));
}

// ---------------- weight pack: fp32[NE] -> hi/lo bf16 planes ----------------
__global__ __launch_bounds__(256) void pack_w_kernel(const float* __restrict__ W,
                                                     short* __restrict__ Wh,
                                                     short* __restrict__ Wl, int NE) {
    int i = blockIdx.x * 256 + threadIdx.x;
    if (i * 4 >= NE) return;
    float4 v = *(const float4*)&W[i * 4];
    short4 h, l;
    unsigned short hs;
    hs = f2bf_rne(v.x); h.x = (short)hs; l.x = (short)f2bf_rne(v.x - bf2f(hs));
    hs = f2bf_rne(v.y); h.y = (short)hs; l.y = (short)f2bf_rne(v.y - bf2f(hs));
    hs = f2bf_rne(v.z); h.z = (short)hs; l.z = (short)f2bf_rne(v.z - bf2f(hs));
    hs = f2bf_rne(v.w); h.w = (short)hs; l.w = (short)f2bf_rne(v.w - bf2f(hs));
    *(short4*)&Wh[i * 4] = h;
    *(short4*)&Wl[i * 4] = l;
}

// ---------------- packed bf16 hi/lo MFMA GEMM: C = A * B^T ----------------
// A,B pre-packed as hi/lo bf16 planes, row stride K shorts. fp32 accumulate,
// D += Ah*Bh + Ah*Bl + Al*Bh. BM=128, BK=32, 4 waves (2x2), 16x16x32 MFMA.
// gridDim.z>1: partial z at C + z*M*N (reduced later). Needs M%128==0, N%BN==0, Kc%32==0.
template<int BN>
__global__ __launch_bounds__(256) void gemm_pk_kernel(const short* __restrict__ Ah,
                                                      const short* __restrict__ Al,
                                                      const short* __restrict__ Bh,
                                                      const short* __restrict__ Bl,
                                                      float* __restrict__ C,
                                                      const float* __restrict__ bias,
                                                      int M, int N, int K, int Kc) {
    constexpr int BM = 128, BK = 32;
    constexpr int LDSS = BK + 8;                // 40 shorts = 80 B row stride
    constexpr int NF = BN / 32;                 // n-frags per wave
    constexpr int A8 = 2;                       // short8 loads/thread/plane (A)
    constexpr int B8 = BN / 64;                 // short8 loads/thread/plane (B)
    __shared__ short AsH[BM * LDSS], AsL[BM * LDSS];
    __shared__ short BsH[BN * LDSS], BsL[BN * LDSS];

    const int tid = threadIdx.x;
    const int lane = tid & 63;
    const int wid = tid >> 6;
    const int wr = wid >> 1, wc = wid & 1;      // 2x2 wave grid
    const int row0 = blockIdx.y * BM, col0 = blockIdx.x * BN;
    const int kbase = blockIdx.z * Kc;

    bf16x8 aPh[A8], aPl[A8], bPh[B8], bPl[B8];
    f32x4 acc[4][NF] = {};

    auto loadG = [&](int k0) {
#pragma unroll
        for (int i = 0; i < A8; i++) {
            int lin = tid + i * 256;
            int r = lin >> 2, cg = (lin & 3) * 8;
            aPh[i] = *(const bf16x8*)&Ah[(size_t)(row0 + r) * K + k0 + cg];
            aPl[i] = *(const bf16x8*)&Al[(size_t)(row0 + r) * K + k0 + cg];
        }
#pragma unroll
        for (int i = 0; i < B8; i++) {
            int lin = tid + i * 256;
            int r = lin >> 2, cg = (lin & 3) * 8;
            bPh[i] = *(const bf16x8*)&Bh[(size_t)(col0 + r) * K + k0 + cg];
            bPl[i] = *(const bf16x8*)&Bl[(size_t)(col0 + r) * K + k0 + cg];
        }
    };
    auto storeLDS = [&]() {
#pragma unroll
        for (int i = 0; i < A8; i++) {
            int lin = tid + i * 256;
            int r = lin >> 2, cg = (lin & 3) * 8;
            *(bf16x8*)&AsH[r * LDSS + cg] = aPh[i];
            *(bf16x8*)&AsL[r * LDSS + cg] = aPl[i];
        }
#pragma unroll
        for (int i = 0; i < B8; i++) {
            int lin = tid + i * 256;
            int r = lin >> 2, cg = (lin & 3) * 8;
            *(bf16x8*)&BsH[r * LDSS + cg] = bPh[i];
            *(bf16x8*)&BsL[r * LDSS + cg] = bPl[i];
        }
    };

    loadG(kbase);
    storeLDS();
    __syncthreads();
    for (int k0 = kbase + BK;; k0 += BK) {
        const bool has_next = (k0 < kbase + Kc);
        if (has_next) loadG(k0);                // next-tile loads in flight
        {
            const int fr = lane & 15;           // row within 16-frag
            const int kg = (lane >> 4) * 8;     // k offset within BK=32
            bf16x8 aH[4], aL[4], bH[NF], bL[NF];
#pragma unroll
            for (int i = 0; i < 4; i++) {
                int row = wr * 64 + i * 16 + fr;
                aH[i] = *(const bf16x8*)&AsH[row * LDSS + kg];
                aL[i] = *(const bf16x8*)&AsL[row * LDSS + kg];
            }
#pragma unroll
            for (int j = 0; j < NF; j++) {
                int row = wc * (BN / 2) + j * 16 + fr;
                bH[j] = *(const bf16x8*)&BsH[row * LDSS + kg];
                bL[j] = *(const bf16x8*)&BsL[row * LDSS + kg];
            }
#pragma unroll
            for (int i = 0; i < 4; i++)
#pragma unroll
                for (int j = 0; j < NF; j++) {
                    acc[i][j] = __builtin_amdgcn_mfma_f32_16x16x32_bf16(aH[i], bH[j], acc[i][j], 0, 0, 0);
                    acc[i][j] = __builtin_amdgcn_mfma_f32_16x16x32_bf16(aH[i], bL[j], acc[i][j], 0, 0, 0);
                    acc[i][j] = __builtin_amdgcn_mfma_f32_16x16x32_bf16(aL[i], bH[j], acc[i][j], 0, 0, 0);
                }
        }
        if (!has_next) break;
        __syncthreads();
        storeLDS();
        __syncthreads();
    }

    float* Cout = C + (size_t)blockIdx.z * M * N;
    const bool direct = (gridDim.z == 1);
    const int crow = (lane >> 4) * 4;
    const int ccol = lane & 15;
#pragma unroll
    for (int i = 0; i < 4; i++) {
#pragma unroll
        for (int j = 0; j < NF; j++) {
            int gn = col0 + wc * (BN / 2) + j * 16 + ccol;
            int gm0 = row0 + wr * 64 + i * 16 + crow;
            float bv = (direct && bias) ? bias[gn] : 0.f;
#pragma unroll
            for (int reg = 0; reg < 4; reg++)
                Cout[(size_t)(gm0 + reg) * N + gn] = acc[i][j][reg] + bv;
        }
    }
}

// ---------------- on-the-fly hi/lo MFMA GEMM (fp32 inputs) — xproj only ----------------
template<int BN>
__global__ __launch_bounds__(256) void gemm_mfma_kernel(const float* __restrict__ A, int lda,
                                                        const float* __restrict__ Bm,
                                                        float* __restrict__ C,
                                                        const float* __restrict__ bias,
                                                        int M, int N, int K, int Kc) {
    constexpr int BM = 128, BK = 32;
    constexpr int LDS = BK + 8;
    constexpr int NF = BN / 32;
    constexpr int BSTG = BN / 32;
    __shared__ short AsH[BM * LDS], AsL[BM * LDS];
    __shared__ short BsH[BN * LDS], BsL[BN * LDS];

    const int tid = threadIdx.x;
    const int lane = tid & 63;
    const int wid = tid >> 6;
    const int wr = wid >> 1, wc = wid & 1;
    const int row0 = blockIdx.y * BM, col0 = blockIdx.x * BN;
    const int kbase = blockIdx.z * Kc;
    const int sr = tid >> 3;
    const int sc = (tid & 7) * 4;

    float aRf[4][4];
    float bRf[BSTG][4];
    f32x4 acc[4][NF] = {};

    auto loadG = [&](int k0) {
#pragma unroll
        for (int i = 0; i < 4; i++)
            *(float4*)aRf[i] = *(const float4*)&A[(size_t)(row0 + sr + 32 * i) * lda + k0 + sc];
#pragma unroll
        for (int i = 0; i < BSTG; i++) {
            int n = sr + 32 * i;
            if (col0 + n < N)
                *(float4*)bRf[i] = *(const float4*)&Bm[(size_t)(col0 + n) * K + k0 + sc];
            else {
                bRf[i][0] = 0.f; bRf[i][1] = 0.f; bRf[i][2] = 0.f; bRf[i][3] = 0.f;
            }
        }
    };
    auto storeLDS = [&]() {
#pragma unroll
        for (int i = 0; i < 4; i++) {
            int row = sr + 32 * i;
            short4 h, l;
            unsigned short hs;
            hs = f2bf_rne(aRf[i][0]); h.x = (short)hs; l.x = (short)f2bf_rne(aRf[i][0] - bf2f(hs));
            hs = f2bf_rne(aRf[i][1]); h.y = (short)hs; l.y = (short)f2bf_rne(aRf[i][1] - bf2f(hs));
            hs = f2bf_rne(aRf[i][2]); h.z = (short)hs; l.z = (short)f2bf_rne(aRf[i][2] - bf2f(hs));
            hs = f2bf_rne(aRf[i][3]); h.w = (short)hs; l.w = (short)f2bf_rne(aRf[i][3] - bf2f(hs));
            *(short4*)&AsH[row * LDS + sc] = h;
            *(short4*)&AsL[row * LDS + sc] = l;
        }
#pragma unroll
        for (int i = 0; i < BSTG; i++) {
            int row = sr + 32 * i;
            short4 h, l;
            unsigned short hs;
            hs = f2bf_rne(bRf[i][0]); h.x = (short)hs; l.x = (short)f2bf_rne(bRf[i][0] - bf2f(hs));
            hs = f2bf_rne(bRf[i][1]); h.y = (short)hs; l.y = (short)f2bf_rne(bRf[i][1] - bf2f(hs));
            hs = f2bf_rne(bRf[i][2]); h.z = (short)hs; l.z = (short)f2bf_rne(bRf[i][2] - bf2f(hs));
            hs = f2bf_rne(bRf[i][3]); h.w = (short)hs; l.w = (short)f2bf_rne(bRf[i][3] - bf2f(hs));
            *(short4*)&BsH[row * LDS + sc] = h;
            *(short4*)&BsL[row * LDS + sc] = l;
        }
    };

    loadG(kbase);
    storeLDS();
    __syncthreads();
    for (int k0 = kbase + BK;; k0 += BK) {
        const bool has_next = (k0 < kbase + Kc);
        if (has_next) loadG(k0);
        {
            const int fr = lane & 15;
            const int kg = (lane >> 4) * 8;
            bf16x8 aH[4], aL[4], bH[NF], bL[NF];
#pragma unroll
            for (int i = 0; i < 4; i++) {
                int row = wr * 64 + i * 16 + fr;
                aH[i] = *(const bf16x8*)&AsH[row * LDS + kg];
                aL[i] = *(const bf16x8*)&AsL[row * LDS + kg];
            }
#pragma unroll
            for (int j = 0; j < NF; j++) {
                int row = wc * (BN / 2) + j * 16 + fr;
                bH[j] = *(const bf16x8*)&BsH[row * LDS + kg];
                bL[j] = *(const bf16x8*)&BsL[row * LDS + kg];
            }
#pragma unroll
            for (int i = 0; i < 4; i++)
#pragma unroll
                for (int j = 0; j < NF; j++) {
                    acc[i][j] = __builtin_amdgcn_mfma_f32_16x16x32_bf16(aH[i], bH[j], acc[i][j], 0, 0, 0);
                    acc[i][j] = __builtin_amdgcn_mfma_f32_16x16x32_bf16(aH[i], bL[j], acc[i][j], 0, 0, 0);
                    acc[i][j] = __builtin_amdgcn_mfma_f32_16x16x32_bf16(aL[i], bH[j], acc[i][j], 0, 0, 0);
                }
        }
        if (!has_next) break;
        __syncthreads();
        storeLDS();
        __syncthreads();
    }

    float* Cout = C + (size_t)blockIdx.z * M * N;
    const bool direct = (gridDim.z == 1);
    const int crow = (lane >> 4) * 4;
    const int ccol = lane & 15;
#pragma unroll
    for (int i = 0; i < 4; i++) {
#pragma unroll
        for (int j = 0; j < NF; j++) {
            int gn = col0 + wc * (BN / 2) + j * 16 + ccol;
            if (gn >= N) continue;
            int gm0 = row0 + wr * 64 + i * 16 + crow;
            float bv = (direct && bias) ? bias[gn] : 0.f;
#pragma unroll
            for (int reg = 0; reg < 4; reg++)
                Cout[(size_t)(gm0 + reg) * N + gn] = acc[i][j][reg] + bv;
        }
    }
}

// ---------------- split-K reduce: sum parts (+bias); fp32 OR packed hi/lo output ----------------
__global__ __launch_bounds__(256) void reduce_kernel(const float* __restrict__ parts,
                                                     float* __restrict__ Cf,
                                                     short* __restrict__ outH,
                                                     short* __restrict__ outL,
                                                     const float* __restrict__ bias,
                                                     long MN, int N, int SK) {
    long i = (long)blockIdx.x * 256 + threadIdx.x;      // float4 index
    if (i * 4 >= MN) return;
    float4 acc = *(const float4*)&parts[i * 4];
    for (int z = 1; z < SK; z++) {
        float4 v = *(const float4*)&parts[(size_t)z * MN + i * 4];
        acc.x += v.x; acc.y += v.y; acc.z += v.z; acc.w += v.w;
    }
    if (bias) {
        int col = (int)((i * 4) % N);
        float4 bv = *(const float4*)&bias[col];
        acc.x += bv.x; acc.y += bv.y; acc.z += bv.z; acc.w += bv.w;
    }
    if (outH) {
        short4 h, l;
        unsigned short hs;
        hs = f2bf_rne(acc.x); h.x = (short)hs; l.x = (short)f2bf_rne(acc.x - bf2f(hs));
        hs = f2bf_rne(acc.y); h.y = (short)hs; l.y = (short)f2bf_rne(acc.y - bf2f(hs));
        hs = f2bf_rne(acc.z); h.z = (short)hs; l.z = (short)f2bf_rne(acc.z - bf2f(hs));
        hs = f2bf_rne(acc.w); h.w = (short)hs; l.w = (short)f2bf_rne(acc.w - bf2f(hs));
        *(short4*)&outH[i * 4] = h;
        *(short4*)&outL[i * 4] = l;
    } else {
        *(float4*)&Cf[i * 4] = acc;
    }
}

// ---------------- causal depthwise conv (DCONV=4) + SiLU ----------------
__global__ __launch_bounds__(256) void conv_silu_kernel(const float* __restrict__ xz,
                                                        const float* __restrict__ cw,
                                                        const float* __restrict__ cb,
                                                        float* __restrict__ xc) {
    size_t idx = (size_t)blockIdx.x * 256 + threadIdx.x;
    if (idx >= (size_t)RTOT * DINNER) return;
    int e = (int)(idx % DINNER);
    size_t r = idx / DINNER;
    int l = (int)(r % NP);
    size_t b = r / NP;
    const float* w = cw + (size_t)e * DCONV;
    float acc = cb[e];
#pragma unroll
    for (int k = 0; k < DCONV; k++) {
        int ls = l + k - (DCONV - 1);
        if (ls >= 0) acc += xz[(b * NP + ls) * 768 + e] * w[k];
    }
    xc[idx] = acc / (1.f + __expf(-acc));   // silu (fast exp)
}

// ---------------- dt projection + softplus -> dead xs-half of xz ----------------
__global__ __launch_bounds__(256) void dt_kernel(const float* __restrict__ proj,
                                                 const float* __restrict__ dtw,
                                                 const float* __restrict__ dtb,
                                                 float* __restrict__ xz) {
    int idx = blockIdx.x * 256 + threadIdx.x;
    if (idx >= RTOT * DINNER) return;
    int d = idx % DINNER;
    size_t r = (size_t)idx / DINNER;
    const float* pr = proj + r * 44;
    const float* w = dtw + (size_t)d * DTR;
    float acc = dtb[d];
#pragma unroll
    for (int k = 0; k < DTR; k++) acc += pr[k] * w[k];
    xz[r * 768 + d] = (acc > 20.f) ? acc : __logf(1.f + __expf(acc));
}

// ---------------- chunked selective scan: lane owns (b,d), 16 states in regs ----------------
__global__ __launch_bounds__(128) void scanA_kernel(const float* __restrict__ xc,
                                                    const float* __restrict__ proj,
                                                    const float* __restrict__ xz,
                                                    const float* __restrict__ A_log,
                                                    float* __restrict__ hEnd,
                                                    float* __restrict__ prodDA) {
    int d = blockIdx.x * 128 + threadIdx.x;       // grid.x = 3
    int c = blockIdx.y, b = blockIdx.z;
    float a[DSTATE], h[DSTATE], p[DSTATE];
#pragma unroll
    for (int s = 0; s < DSTATE; s++) {
        a[s] = -expf(A_log[(size_t)d * DSTATE + s]);   // precise (once per lane)
        h[s] = 0.f;
        p[s] = 1.f;
    }
    size_t rbase = (size_t)b * NP + (size_t)c * LC;
    for (int l = 0; l < LC; l++) {
        size_t r = rbase + l;
        float dtv = xz[r * 768 + d];              // dt (stored in xs-half)
        float du = dtv * xc[r * DINNER + d];
        const float* pb = proj + r * 44 + DTR;    // wave-uniform
        float Bv[DSTATE];
        *(float4*)&Bv[0]  = *(const float4*)&pb[0];
        *(float4*)&Bv[4]  = *(const float4*)&pb[4];
        *(float4*)&Bv[8]  = *(const float4*)&pb[8];
        *(float4*)&Bv[12] = *(const float4*)&pb[12];
#pragma unroll
        for (int s = 0; s < DSTATE; s++) {
            float dA = __expf(dtv * a[s]);        // fast exp (hot loop)
            h[s] = h[s] * dA + du * Bv[s];
            p[s] *= dA;
        }
    }
    float* he = hEnd   + (((size_t)b * CHUNKS + c) * DINNER + d) * DSTATE;
    float* pd = prodDA + (((size_t)b * CHUNKS + c) * DINNER + d) * DSTATE;
#pragma unroll
    for (int g = 0; g < 4; g++) {
        *(float4*)&he[g * 4] = *(float4*)&h[g * 4];
        *(float4*)&pd[g * 4] = *(float4*)&p[g * 4];
    }
}

__global__ __launch_bounds__(256) void scanB_kernel(const float* __restrict__ hEnd,
                                                    float* __restrict__ prodDA) {
    int idx = blockIdx.x * 256 + threadIdx.x;
    if (idx >= BB * DINNER * DSTATE) return;
    int b = idx / (DINNER * DSTATE);
    int rem = idx % (DINNER * DSTATE);
    float run = 0.f;
    for (int c = 0; c < CHUNKS; c++) {
        size_t off = ((size_t)b * CHUNKS + c) * (DINNER * DSTATE) + rem;
        float p = prodDA[off];
        float e = hEnd[off];
        prodDA[off] = run;          // hInit for chunk c
        run = run * p + e;
    }
}

// Pass C: rerun from hInit; fused (y+u*D)*silu(z); emits y2 PACKED hi/lo planes.
__global__ __launch_bounds__(128) void scanC_kernel(const float* __restrict__ xc,
                                                    const float* __restrict__ proj,
                                                    const float* __restrict__ hInit,
                                                    const float* __restrict__ A_log,
                                                    const float* __restrict__ Dv,
                                                    const float* __restrict__ xz,
                                                    short* __restrict__ yh,
                                                    short* __restrict__ yl) {
    int d = blockIdx.x * 128 + threadIdx.x;       // grid.x = 3
    int c = blockIdx.y, b = blockIdx.z;
    float a[DSTATE], h[DSTATE];
#pragma unroll
    for (int s = 0; s < DSTATE; s++)
        a[s] = -expf(A_log[(size_t)d * DSTATE + s]);   // precise (once per lane)
    const float* hi = hInit + (((size_t)b * CHUNKS + c) * DINNER + d) * DSTATE;
#pragma unroll
    for (int g = 0; g < 4; g++)
        *(float4*)&h[g * 4] = *(const float4*)&hi[g * 4];
    float Dd = Dv[d];
    size_t rbase = (size_t)b * NP + (size_t)c * LC;
    for (int l = 0; l < LC; l++) {
        size_t r = rbase + l;
        float dtv = xz[r * 768 + d];              // dt (stored in xs-half)
        float u = xc[r * DINNER + d];
        float du = dtv * u;
        const float* pb = proj + r * 44 + DTR;              // wave-uniform
        const float* pc = proj + r * 44 + DTR + DSTATE;
        float Bv[DSTATE], Cv[DSTATE];
        *(float4*)&Bv[0]  = *(const float4*)&pb[0];
        *(float4*)&Bv[4]  = *(const float4*)&pb[4];
        *(float4*)&Bv[8]  = *(const float4*)&pb[8];
        *(float4*)&Bv[12] = *(const float4*)&pb[12];
        *(float4*)&Cv[0]  = *(const float4*)&pc[0];
        *(float4*)&Cv[4]  = *(const float4*)&pc[4];
        *(float4*)&Cv[8]  = *(const float4*)&pc[8];
        *(float4*)&Cv[12] = *(const float4*)&pc[12];
        float y = 0.f;
#pragma unroll
        for (int s = 0; s < DSTATE; s++) {
            float dA = __expf(dtv * a[s]);        // fast exp (hot loop)
            h[s] = h[s] * dA + du * Bv[s];
            y = fmaf(h[s], Cv[s], y);
        }
        float z = xz[r * 768 + DINNER + d];
        float val = (y + u * Dd) * (z / (1.f + __expf(-z)));
        unsigned short hs = f2bf_rne(val);
        yh[r * DINNER + d] = (short)hs;
        yl[r * DINNER + d] = (short)f2bf_rne(val - bf2f(hs));
    }
}

// ---------------- final layernorm: per-row stats (packed x input) ----------------
__global__ __launch_bounds__(256) void ln_stats_kernel(const short* __restrict__ xh,
                                                       const short* __restrict__ xl,
                                                       float* __restrict__ stats) {
    int r = blockIdx.x * 4 + (threadIdx.x >> 6);
    int lane = threadIdx.x & 63;
    if (r >= RTOT) return;
    float s = 0.f, ss = 0.f;
    for (int c = lane; c < DM; c += 64) {
        size_t i = (size_t)r * DM + c;
        float v = bf2f((unsigned short)xh[i]) + bf2f((unsigned short)xl[i]);
        s += v;
        ss += v * v;
    }
#pragma unroll
    for (int o = 32; o > 0; o >>= 1) {
        s += __shfl_down(s, o);
        ss += __shfl_down(ss, o);
    }
    if (lane == 0) {
        float mu = s / (float)DM;
        float var = ss / (float)DM - mu * mu;
        stats[r * 2] = mu;
        stats[r * 2 + 1] = rsqrtf(var + 1e-5f);
    }
}

// ---------------- normalized mean over sequence (packed x input) ----------------
__global__ __launch_bounds__(256) void ln_mean_kernel(const short* __restrict__ xh,
                                                      const short* __restrict__ xl,
                                                      const float* __restrict__ stats,
                                                      const float* __restrict__ nw,
                                                      const float* __restrict__ nb,
                                                      float* __restrict__ out) {
    int idx = blockIdx.x * 256 + threadIdx.x;
    if (idx >= BB * DM) return;
    int c = idx % DM;
    int b = idx / DM;
    float acc = 0.f;
    for (int l = 0; l < NP; l++) {
        size_t r = (size_t)b * NP + l;
        size_t i = r * DM + c;
        float v = bf2f((unsigned short)xh[i]) + bf2f((unsigned short)xl[i]);
        acc += (v - stats[r * 2]) * stats[r * 2 + 1];
    }
    out[idx] = acc * (1.f / (float)NP) * nw[c] + nb[c];
}

extern "C" void kernel_launch(void* const* d_in, const int* in_sizes, int n_in,
                              void* d_out, int out_size, void* d_ws, size_t ws_size,
                              hipStream_t stream) {
    const float* img     = (const float*)d_in[0];
    const float* patch_w = (const float*)d_in[1];
    const float* patch_b = (const float*)d_in[2];
    const float* in_w    = (const float*)d_in[3];
    const float* conv_w  = (const float*)d_in[4];
    const float* conv_b  = (const float*)d_in[5];
    const float* xpw     = (const float*)d_in[6];
    const float* dtw     = (const float*)d_in[7];
    const float* dtb     = (const float*)d_in[8];
    const float* A_log   = (const float*)d_in[9];
    const float* Dv      = (const float*)d_in[10];
    const float* outw    = (const float*)d_in[11];
    const float* norm_w  = (const float*)d_in[12];
    const float* norm_b  = (const float*)d_in[13];
    float* out = (float*)d_out;

    float* ws = (float*)d_ws;
    const size_t R = RTOT;
    const size_t PLX = R * DM;                 // x plane: 2,408,448 shorts
    const size_t PLY = R * DINNER;             // y2 plane: 4,816,896 shorts
    float* xA      = ws;                       // packed x planes (2.41M fu)
    float* xB      = xA + PLX;                 // packed x planes
    float* xz      = xB + PLX;                 // R*768 fp32 (layers) / packed im2col (patch)
    float* xc      = xz + R * 768;             // R*384 fp32
    float* proj    = xc + R * DINNER;          // R*44 fp32
    float* scratch = proj + R * 44;            // 11.01M fu shared region
    float* hEnd    = scratch;                                        // 5.505M fu
    float* prodDA  = hEnd + (size_t)BB * CHUNKS * DINNER * DSTATE;   // 5.505M fu
    float* wpkA    = scratch + (size_t)2 * BB * CHUNKS * DINNER * DSTATE;  // 147,456 fu
    float* wpkB    = wpkA + 2 * DINNER * DM / 2 * 2;                 // 73,728 fu  (outw planes)
    float* stats   = wpkB + DM * DINNER;                             // R*2

    short* y2h = (short*)scratch;              // y2 packed planes (in dead hEnd)
    short* y2l = y2h + PLY;
    float* pkparts = prodDA;                   // out_proj SK2 partials (dead hInit)

    // patch embed: pack patch_w + packed im2col + SK4 GEMM + packed reduce(+bias)
    {
        short* wh = (short*)wpkA; short* wl = wh + DM * 768;
        pack_w_kernel<<<dim3((DM * 768 / 4 + 255) / 256), 256, 0, stream>>>(
            patch_w, wh, wl, DM * 768);
        short* colH = (short*)xz; short* colL = colH + R * 768;
        size_t n = R * 768;
        im2col_pack_kernel<<<dim3((unsigned)((n + 255) / 256)), 256, 0, stream>>>(
            img, colH, colL);
        gemm_pk_kernel<64><<<dim3(3, RTOT / 128, 4), 256, 0, stream>>>(
            colH, colL, wh, wl, scratch + 11008 * 1024 / 4 * 0 + 0, nullptr,
            RTOT, DM, 768, 192);
        // NOTE: partials written at scratch[0..] — but colH/colL live in xz, disjoint. OK.
        long MN = (long)RTOT * DM;
        reduce_kernel<<<dim3((unsigned)((MN / 4 + 255) / 256)), 256, 0, stream>>>(
            scratch, nullptr, (short*)xA, (short*)xA + PLX, patch_b, MN, DM, 4);
    }

    float* xin = xA;
    float* xout = xB;
    for (int layer = 0; layer < DEPTH; layer++) {
        const float* in_w_l  = in_w + (size_t)layer * 2 * DINNER * DM;
        const float* conv_wl = conv_w + (size_t)layer * DINNER * DCONV;
        const float* conv_bl = conv_b + (size_t)layer * DINNER;
        const float* xpw_l   = xpw + (size_t)layer * (DTR + 2 * DSTATE) * DINNER;
        const float* dtw_l   = dtw + (size_t)layer * DINNER * DTR;
        const float* dtb_l   = dtb + (size_t)layer * DINNER;
        const float* Alog_l  = A_log + (size_t)layer * DINNER * DSTATE;
        const float* Dv_l    = Dv + (size_t)layer * DINNER;
        const float* outw_l  = outw + (size_t)layer * DM * DINNER;

        short* xinH = (short*)xin; short* xinL = xinH + PLX;
        short* xoutH = (short*)xout; short* xoutL = xoutH + PLX;

        // pack in_w, then xz = x @ in_w^T (M=12544, N=768, K=192), direct fp32
        {
            short* wh = (short*)wpkA; short* wl = wh + 2 * DINNER * DM;
            pack_w_kernel<<<dim3((2 * DINNER * DM / 4 + 255) / 256), 256, 0, stream>>>(
                in_w_l, wh, wl, 2 * DINNER * DM);
            gemm_pk_kernel<128><<<dim3(768 / 128, RTOT / 128, 1), 256, 0, stream>>>(
                xinH, xinL, wh, wl, xz, nullptr, RTOT, 2 * DINNER, DM, DM);
        }
        // xc = silu(causal depthwise conv(xs))
        {
            size_t n = R * DINNER;
            conv_silu_kernel<<<dim3((unsigned)((n + 255) / 256)), 256, 0, stream>>>(
                xz, conv_wl, conv_bl, xc);
        }
        // proj = xc @ xpw^T (N=44, K=384) SK=4, Kc=96 (on-the-fly path)
        gemm_mfma_kernel<64><<<dim3(1, RTOT / 128, 4), 256, 0, stream>>>(
            xc, DINNER, xpw_l, scratch, nullptr, RTOT, DTR + 2 * DSTATE, DINNER, 96);
        {
            long MN = (long)RTOT * 44;
            reduce_kernel<<<dim3((unsigned)((MN / 4 + 255) / 256)), 256, 0, stream>>>(
                scratch, proj, nullptr, nullptr, nullptr, MN, 44, 4);
        }
        // dt = softplus(...) -> xz xs-half
        dt_kernel<<<dim3((RTOT * DINNER + 255) / 256), 256, 0, stream>>>(
            proj, dtw_l, dtb_l, xz);
        // chunked scan; scanC emits y2 packed into dead hEnd region
        scanA_kernel<<<dim3(3, CHUNKS, BB), 128, 0, stream>>>(
            xc, proj, xz, Alog_l, hEnd, prodDA);
        scanB_kernel<<<dim3((BB * DINNER * DSTATE + 255) / 256), 256, 0, stream>>>(
            hEnd, prodDA);
        scanC_kernel<<<dim3(3, CHUNKS, BB), 128, 0, stream>>>(
            xc, proj, prodDA, Alog_l, Dv_l, xz, y2h, y2l);
        // pack outw, then x_next = y2 @ outw^T (N=192, K=384) SK=2, packed reduce -> xout
        {
            short* wh = (short*)wpkB; short* wl = wh + DM * DINNER;
            pack_w_kernel<<<dim3((DM * DINNER / 4 + 255) / 256), 256, 0, stream>>>(
                outw_l, wh, wl, DM * DINNER);
            gemm_pk_kernel<64><<<dim3(DM / 64, RTOT / 128, 2), 256, 0, stream>>>(
                y2h, y2l, wh, wl, pkparts, nullptr, RTOT, DM, DINNER, 192);
            long MN = (long)RTOT * DM;
            reduce_kernel<<<dim3((unsigned)((MN / 4 + 255) / 256)), 256, 0, stream>>>(
                pkparts, nullptr, xoutH, xoutL, nullptr, MN, DM, 2);
        }

        float* t = xin; xin = xout; xout = t;
    }

    // final layernorm + mean over sequence (packed x)
    short* xfH = (short*)xin; short* xfL = xfH + PLX;
    ln_stats_kernel<<<dim3(RTOT / 4), 256, 0, stream>>>(xfH, xfL, stats);
    ln_mean_kernel<<<dim3((BB * DM + 255) / 256), 256, 0, stream>>>(
        xfH, xfL, stats, norm_w, norm_b, out);
}